// Round 1
// baseline (341.794 us; speedup 1.0000x reference)
//
#include <hip/hip_runtime.h>
#include <math.h>
#include <stdint.h>

#define VOCAB 50257
#define KD 5
#define NBATCH 256
#define NT 1024
#define NW (NT / 64)
#define NTILES ((VOCAB + NT - 1) / NT) /* 50 */

// One block per batch element. Lazy accept scan (E[rows] ~= 1.0 for these
// inputs), then f64 fallback-sampling over the rejected row.
__global__ __launch_bounds__(NT) void spec_decode_kernel(
    const int* __restrict__ dtok,     // [B,K] int32
    const float* __restrict__ dlp,    // [B,K] f32
    const float* __restrict__ logits, // [B,K,V] f32
    const float* __restrict__ rnd,    // [B,K] f32
    const float* __restrict__ usmp,   // [B] f32
    int* __restrict__ out)            // [B*K + B + B] int32
{
    const int b    = blockIdx.x;
    const int tid  = threadIdx.x;
    const int lane = tid & 63;
    const int wv   = tid >> 6;

    __shared__ double s_w[NW];
    __shared__ double s_tileA[NTILES];
    __shared__ double s_tileR[NTILES];
    __shared__ double s_dbc[2];
    __shared__ int    s_ibc[2];
    __shared__ int    s_found;

    // ---------------- Phase 1: lazy accept/reject scan ----------------
    double Zsel  = 0.0; // Z of the last row processed (== rejected row when n_acc < K)
    int    n_acc = KD;
    for (int r = 0; r < KD; ++r) {
        const float* row = logits + ((size_t)b * KD + r) * (size_t)VOCAB;
        // peel to 16B alignment (V odd -> rows are only 4B aligned)
        int head = (int)((4u - ((((uintptr_t)row) >> 2) & 3u)) & 3u);
        double local = 0.0;
        if (tid < head) local += (double)expf(row[tid]);
        int nvec = (VOCAB - head) >> 2;
        const float4* row4 = (const float4*)(row + head);
        for (int i = tid; i < nvec; i += NT) {
            float4 x = row4[i];
            local += (double)expf(x.x) + (double)expf(x.y)
                   + (double)expf(x.z) + (double)expf(x.w);
        }
        int tail_start = head + (nvec << 2);
        int tail_cnt   = VOCAB - tail_start;
        if (tid < tail_cnt) local += (double)expf(row[tail_start + tid]);

        // block reduce (wave shuffle + LDS)
        for (int off = 32; off; off >>= 1) local += __shfl_down(local, off, 64);
        if (lane == 0) s_w[wv] = local;
        __syncthreads();
        if (tid == 0) {
            double Z = 0.0;
            for (int w = 0; w < NW; ++w) Z += s_w[w];
            int    tok  = dtok[b * KD + r];
            double tlp  = (double)row[tok] - log(Z);
            double ap   = exp(tlp - (double)dlp[b * KD + r]);
            if (ap > 1.0) ap = 1.0;
            s_dbc[0] = Z;
            s_ibc[0] = ((double)rnd[b * KD + r] < ap) ? 1 : 0;
        }
        __syncthreads();
        Zsel = s_dbc[0];
        int acc = s_ibc[0];
        __syncthreads(); // protect s_w / s_dbc reuse next iteration
        if (!acc) { n_acc = r; break; }
    }

    // ---------------- Phase 2: write accepted tokens / n ----------------
    if (tid == 0) {
        for (int r = 0; r < KD; ++r)
            out[b * KD + r] = (r < n_acc) ? dtok[b * KD + r] : 0;
        out[NBATCH * KD + b] = n_acc;
        if (n_acc >= KD) out[NBATCH * KD + NBATCH + b] = 0; // PAD, no resample
        s_found = 0x7FFFFFFF;
    }
    if (n_acc >= KD) return; // block-uniform

    const int    rp   = n_acc; // == min(first_reject, K-1) since n_acc < K
    const float* row  = logits + ((size_t)b * KD + rp) * (size_t)VOCAB;
    const double invZ = 1.0 / Zsel;
    const double dp   = exp((double)dlp[b * KD + rp]);

    // ---------------- Phase 3: tile sums (adjusted + raw) ----------------
    for (int t = wv; t < NTILES; t += NW) {
        double aS = 0.0, rS = 0.0;
        int base = t * NT;
        for (int j = 0; j < NT / 64; ++j) {
            int idx = base + j * 64 + lane;
            if (idx < VOCAB) {
                double p = exp((double)row[idx]) * invZ;
                rS += p;
                double a = p - dp;
                if (a > 0.0) aS += a;
            }
        }
        for (int off = 32; off; off >>= 1) {
            aS += __shfl_down(aS, off, 64);
            rS += __shfl_down(rS, off, 64);
        }
        if (lane == 0) { s_tileA[t] = aS; s_tileR[t] = rS; }
    }
    __syncthreads(); // also orders s_found init before atomicMin below

    // ---------------- Phase 4: pick crossing tile (thread 0) ----------------
    if (tid == 0) {
        double S = 0.0;
        for (int t = 0; t < NTILES; ++t) S += s_tileA[t];
        int useAdj = (S > 0.0) ? 1 : 0;
        double Tot = S;
        if (!useAdj) {
            Tot = 0.0;
            for (int t = 0; t < NTILES; ++t) Tot += s_tileR[t];
        }
        double T = (double)usmp[b] * Tot;
        const double* tiles = useAdj ? s_tileA : s_tileR;
        double P = 0.0;
        int    ct = NTILES - 1;
        for (int t = 0; t < NTILES; ++t) {
            if (P + tiles[t] >= T || t == NTILES - 1) { ct = t; break; }
            P += tiles[t];
        }
        s_dbc[0] = P;
        s_dbc[1] = T;
        s_ibc[0] = ct;
        s_ibc[1] = useAdj;
    }
    __syncthreads();

    // ---------------- Phase 5: in-tile ordered scan -> sampled index ------
    {
        double Pb     = s_dbc[0];
        double T      = s_dbc[1];
        int    ct     = s_ibc[0];
        int    useAdj = s_ibc[1];
        int    idx    = ct * NT + tid;
        double g      = 0.0;
        if (idx < VOCAB) {
            double p = exp((double)row[idx]) * invZ;
            if (useAdj) {
                double a = p - dp;
                g = (a > 0.0) ? a : 0.0;
            } else {
                g = p;
            }
        }
        // wave inclusive scan
        double sc = g;
        for (int off = 1; off < 64; off <<= 1) {
            double v = __shfl_up(sc, (unsigned)off, 64);
            if (lane >= off) sc += v;
        }
        if (lane == 63) s_w[wv] = sc;
        __syncthreads();
        double woff = 0.0;
        for (int w = 0; w < wv; ++w) woff += s_w[w];
        double incl = Pb + woff + sc;
        if (idx < VOCAB && incl >= T) atomicMin(&s_found, idx);
        __syncthreads();
        if (tid == 0) {
            int smp = s_found;
            if (smp == 0x7FFFFFFF) { // rounding guard: fall back to tile end
                smp = ct * NT + NT - 1;
                if (smp > VOCAB - 1) smp = VOCAB - 1;
            }
            out[NBATCH * KD + NBATCH + b] = smp;
        }
    }
}

extern "C" void kernel_launch(void* const* d_in, const int* in_sizes, int n_in,
                              void* d_out, int out_size, void* d_ws, size_t ws_size,
                              hipStream_t stream) {
    const int*   dtok   = (const int*)d_in[0];
    const float* dlp    = (const float*)d_in[1];
    const float* logits = (const float*)d_in[2];
    const float* rnd    = (const float*)d_in[3];
    const float* usmp   = (const float*)d_in[4];
    int*         out    = (int*)d_out;
    (void)in_sizes; (void)n_in; (void)out_size; (void)d_ws; (void)ws_size;
    spec_decode_kernel<<<dim3(NBATCH), dim3(NT), 0, stream>>>(
        dtok, dlp, logits, rnd, usmp, out);
}